// Round 1
// baseline (11.452 us; speedup 1.0000x reference)
//
#include <hip/hip_runtime.h>
#include <hip/hip_bf16.h>
#include <cmath>

#define B_DIM 64
#define S_DIM 512
#define H_DIM 768
#define MAX_DEPTH 48
#define EPS 1e-7f

// Stage 1: one 64-lane wave per (b, l). Computes masked term into ws[b*MAX_DEPTH + l].
__global__ __launch_bounds__(64) void kt_dots_kernel(
    const float* __restrict__ outputs,      // (B, S, H) -- only token 0 used
    const float* __restrict__ embedding,    // (N_NODES, H)
    const int*   __restrict__ path_nodes,   // (B, MAX_DEPTH)
    const int*   __restrict__ path_signs,   // (B, MAX_DEPTH)
    const int*   __restrict__ path_lengths, // (B,)
    float*       __restrict__ terms)        // (B*MAX_DEPTH,) scratch
{
    const int idx  = blockIdx.x;            // 0 .. B*MAX_DEPTH-1
    const int b    = idx / MAX_DEPTH;
    const int l    = idx % MAX_DEPTH;
    const int lane = threadIdx.x;           // 0..63

    const int len = path_lengths[b];
    if (l >= len) {
        if (lane == 0) terms[idx] = 0.0f;
        return;
    }

    const int node = path_nodes[idx];
    const float4* __restrict__ e4 = (const float4*)(embedding + (size_t)node * H_DIM);
    const float4* __restrict__ h4 = (const float4*)(outputs + (size_t)b * S_DIM * H_DIM);

    // H_DIM/4 = 192 float4 elements; 3 per lane.
    float acc = 0.0f;
    #pragma unroll
    for (int i = 0; i < 3; ++i) {
        const int j = lane + i * 64;
        float4 a = e4[j];
        float4 c = h4[j];
        acc += a.x * c.x + a.y * c.y + a.z * c.z + a.w * c.w;
    }

    // 64-lane butterfly reduce
    #pragma unroll
    for (int off = 32; off > 0; off >>= 1)
        acc += __shfl_down(acc, off, 64);

    if (lane == 0) {
        const float sgn = (float)(2 * path_signs[idx] - 1);
        const float x   = sgn * acc;
        // log(sigmoid(x) + eps), straightforward f32 like the reference
        const float sig = 1.0f / (1.0f + __expf(-x));
        terms[idx] = __logf(sig + EPS);
    }
}

// Stage 2: single wave; lane b reduces its row, then cross-lane reduce.
__global__ __launch_bounds__(64) void kt_reduce_kernel(
    const float* __restrict__ terms,        // (B*MAX_DEPTH,)
    const int*   __restrict__ path_lengths, // (B,)
    float*       __restrict__ out)          // scalar
{
    const int b = threadIdx.x;  // 0..63 == B_DIM-1
    float s = 0.0f;
    #pragma unroll
    for (int l = 0; l < MAX_DEPTH; ++l)
        s += terms[b * MAX_DEPTH + l];
    s /= (float)path_lengths[b];

    #pragma unroll
    for (int off = 32; off > 0; off >>= 1)
        s += __shfl_down(s, off, 64);

    if (b == 0) out[0] = -s / (float)B_DIM;
}

extern "C" void kernel_launch(void* const* d_in, const int* in_sizes, int n_in,
                              void* d_out, int out_size, void* d_ws, size_t ws_size,
                              hipStream_t stream) {
    const float* outputs      = (const float*)d_in[0];
    const float* embedding    = (const float*)d_in[1];
    const int*   path_nodes   = (const int*)d_in[2];
    const int*   path_signs   = (const int*)d_in[3];
    const int*   path_lengths = (const int*)d_in[4];
    float*       out          = (float*)d_out;
    float*       terms        = (float*)d_ws;   // B*MAX_DEPTH floats = 12 KiB

    kt_dots_kernel<<<B_DIM * MAX_DEPTH, 64, 0, stream>>>(
        outputs, embedding, path_nodes, path_signs, path_lengths, terms);
    kt_reduce_kernel<<<1, 64, 0, stream>>>(terms, path_lengths, out);
}